// Round 3
// baseline (386.702 us; speedup 1.0000x reference)
//
#include <hip/hip_runtime.h>

// ---------- types ----------
typedef __bf16 bf16x8 __attribute__((ext_vector_type(8)));
typedef __bf16 bf16x4 __attribute__((ext_vector_type(4)));
typedef float  f32x4  __attribute__((ext_vector_type(4)));

// async global->LDS, 16B per lane; LDS dest = wave-uniform base + lane*16
__device__ __forceinline__ void cp16(void* lds, const void* g) {
  __builtin_amdgcn_global_load_lds(
      (const __attribute__((address_space(1))) unsigned int*)g,
      (__attribute__((address_space(3))) unsigned int*)lds, 16, 0, 0);
}

// =====================================================================
// Convert f32 -> bf16, 4 elems/thread. n must be multiple of 1024.
// =====================================================================
__global__ __launch_bounds__(256) void cvt_kernel(const float* __restrict__ src,
                                                  __bf16* __restrict__ dst) {
  const size_t i = ((size_t)blockIdx.x * 256 + threadIdx.x) * 4;
  f32x4 v = *(const f32x4*)(src + i);
  bf16x4 o;
  o[0] = (__bf16)v[0]; o[1] = (__bf16)v[1];
  o[2] = (__bf16)v[2]; o[3] = (__bf16)v[3];
  *(bf16x4*)(dst + i) = o;
}

// =====================================================================
// GEMM: out[n*outStride + m] = sum_k Aop[m][k] * Bop[n][k], k = 512 fixed.
// m97 structure: 128x128 tile, BK=32, 4 waves in 2x2, 4x4 frags/wave.
// Inputs bf16 (pre-converted), output bf16.
// =====================================================================
__global__ __launch_bounds__(256) void gemm_nt(const __bf16* __restrict__ Aop,
                                               const __bf16* __restrict__ Bop,
                                               __bf16* __restrict__ out,
                                               int outStride) {
  __shared__ __align__(16) __bf16 At[128 * 32];
  __shared__ __align__(16) __bf16 Bt[128 * 32];
  const int tid = threadIdx.x;
  const int lane = tid & 63;
  const int w = tid >> 6;
  const int q = lane >> 4, ln = lane & 15;
  const int wm = w >> 1, wn = w & 1;
  const int nbase = blockIdx.x * 128, mbase = blockIdx.y * 128;

  f32x4 acc[4][4] = {};

  for (int kt = 0; kt < 16; ++kt) {
    const int k0 = kt * 32;
    __syncthreads();
#pragma unroll
    for (int s = 0; s < 2; ++s) {
      const int cbase = (tid & 192) + s * 256;   // wave-uniform chunk base
      const int c = cbase + lane;                // 16B chunk id, 512 total
      const int row = c >> 2;
      const int kc = (c & 3) * 8;
      cp16(&At[cbase * 8], Aop + (size_t)(mbase + row) * 512 + k0 + kc);
      cp16(&Bt[cbase * 8], Bop + (size_t)(nbase + row) * 512 + k0 + kc);
    }
    __syncthreads();  // compiler drains vmcnt before s_barrier

    bf16x8 af[4], bfr[4];
#pragma unroll
    for (int f = 0; f < 4; ++f) {
      af[f]  = *(const bf16x8*)&At[(wm * 64 + f * 16 + ln) * 32 + q * 8];
      bfr[f] = *(const bf16x8*)&Bt[(wn * 64 + f * 16 + ln) * 32 + q * 8];
    }
#pragma unroll
    for (int fm = 0; fm < 4; ++fm)
#pragma unroll
      for (int fn = 0; fn < 4; ++fn)
        acc[fm][fn] = __builtin_amdgcn_mfma_f32_16x16x32_bf16(
            af[fm], bfr[fn], acc[fm][fn], 0, 0, 0);
  }

  // epilogue: lane holds D[m = .. + q*4 + r][n = .. + ln]
#pragma unroll
  for (int fm = 0; fm < 4; ++fm) {
#pragma unroll
    for (int fn = 0; fn < 4; ++fn) {
      const int m = mbase + wm * 64 + fm * 16 + q * 4;
      const int n = nbase + wn * 64 + fn * 16 + ln;
      f32x4 v = acc[fm][fn];
      bf16x4 o;
      o[0] = (__bf16)v[0]; o[1] = (__bf16)v[1];
      o[2] = (__bf16)v[2]; o[3] = (__bf16)v[3];
      *(bf16x4*)&out[(size_t)n * outStride + m] = o;
    }
  }
}

// =====================================================================
// Attention: per (batch, 128-n chunk): S = Q Kp^T /16 + logP, P = exp(S)
// (scores tiny, logP in [-2.3,-0.105] -> no max pass needed);
// write unnormalized P (f32) to A-out region, atomic rowsums;
// then PV partial via MFMA (P round-trips LDS as bf16), atomic F1.
// =====================================================================
#define QLDS_STRIDE 264   // 256 + 8 pad (row stride 528 B = 33*16, aligned)
#define PLDS_STRIDE 136   // 128 + 8 pad (row stride 272 B = 17*16, aligned)
__global__ __launch_bounds__(256) void attn_kernel(
    const __bf16* __restrict__ Qw, const __bf16* __restrict__ Kp,
    const __bf16* __restrict__ Vt, const float* __restrict__ Pb,
    float* __restrict__ Aout, float* __restrict__ F1,
    float* __restrict__ rowsum) {
  __shared__ __align__(16) __bf16 Qlds[32 * QLDS_STRIDE];
  __shared__ __align__(16) __bf16 Ktile[128 * 32];
  __shared__ __align__(16) __bf16 Plds[32 * PLDS_STRIDE];

  const int tid = threadIdx.x;
  const int lane = tid & 63;
  const int w = tid >> 6;
  const int q = lane >> 4, ln = lane & 15;
  const int b = blockIdx.y;
  const int n0 = blockIdx.x * 128;

  // stage Q_b [32 x 256] into padded LDS
  const __bf16* Qb = Qw + (size_t)b * 32 * 256;
#pragma unroll
  for (int s = 0; s < 4; ++s) {
    const int c = tid + s * 256;            // 1024 chunks of 8 elems
    const int row = c >> 5, col = (c & 31) * 8;
    bf16x8 v = *(const bf16x8*)(Qb + (size_t)c * 8);
    *(bf16x8*)&Qlds[row * QLDS_STRIDE + col] = v;
  }

  // ---- QK^T : D[i][n], i<32 (2 frags), wave w owns 32 n-cols (2 frags) ----
  f32x4 acc[2][2] = {};
  const __bf16* Kpb = Kp + (size_t)(b * 4096 + n0) * 256;
  for (int kk = 0; kk < 8; ++kk) {
    __syncthreads();
#pragma unroll
    for (int s = 0; s < 2; ++s) {
      const int cbase = (tid & 192) + s * 256;
      const int c = cbase + lane;
      const int row = c >> 2;
      const int kc = (c & 3) * 8;
      cp16(&Ktile[cbase * 8], Kpb + (size_t)row * 256 + kk * 32 + kc);
    }
    __syncthreads();
    bf16x8 a0 = *(const bf16x8*)&Qlds[(ln) * QLDS_STRIDE + kk * 32 + q * 8];
    bf16x8 a1 = *(const bf16x8*)&Qlds[(16 + ln) * QLDS_STRIDE + kk * 32 + q * 8];
    bf16x8 b0 = *(const bf16x8*)&Ktile[(w * 32 + ln) * 32 + q * 8];
    bf16x8 b1 = *(const bf16x8*)&Ktile[(w * 32 + 16 + ln) * 32 + q * 8];
    acc[0][0] = __builtin_amdgcn_mfma_f32_16x16x32_bf16(a0, b0, acc[0][0], 0, 0, 0);
    acc[0][1] = __builtin_amdgcn_mfma_f32_16x16x32_bf16(a0, b1, acc[0][1], 0, 0, 0);
    acc[1][0] = __builtin_amdgcn_mfma_f32_16x16x32_bf16(a1, b0, acc[1][0], 0, 0, 0);
    acc[1][1] = __builtin_amdgcn_mfma_f32_16x16x32_bf16(a1, b1, acc[1][1], 0, 0, 0);
  }

  // ---- P = exp(S/16 + logP); write Aout (f32) + Plds (bf16); rowsums ----
  float lp[2];
#pragma unroll
  for (int fn = 0; fn < 2; ++fn) {
    const int n = n0 + w * 32 + fn * 16 + ln;
    float p = Pb[b * 4096 + n];
    p = fminf(fmaxf(p, 0.1f), 0.9f);
    lp[fn] = __logf(p);
  }
  float rs[2][4] = {};
#pragma unroll
  for (int fm = 0; fm < 2; ++fm) {
#pragma unroll
    for (int fn = 0; fn < 2; ++fn) {
      f32x4 s = acc[fm][fn];
#pragma unroll
      for (int r = 0; r < 4; ++r) {
        const float pv = __expf(s[r] * 0.0625f + lp[fn]);
        const int i = fm * 16 + q * 4 + r;
        const int nn = w * 32 + fn * 16 + ln;
        Aout[(size_t)(b * 32 + i) * 4096 + n0 + nn] = pv;
        Plds[i * PLDS_STRIDE + nn] = (__bf16)pv;
        rs[fm][r] += pv;
      }
    }
  }
#pragma unroll
  for (int m = 1; m < 16; m <<= 1)
#pragma unroll
    for (int fm = 0; fm < 2; ++fm)
#pragma unroll
      for (int r = 0; r < 4; ++r)
        rs[fm][r] += __shfl_xor(rs[fm][r], m, 64);
  if (ln == 0) {
#pragma unroll
    for (int fm = 0; fm < 2; ++fm)
#pragma unroll
      for (int r = 0; r < 4; ++r)
        atomicAdd(&rowsum[b * 32 + fm * 16 + q * 4 + r], rs[fm][r]);
  }
  __syncthreads();

  // ---- PV: D2[i][d] = sum_nn P[i][nn] * Vt[d][n0+nn] ----
  f32x4 acc2[2][4] = {};
  const __bf16* Vtb = Vt + (size_t)b * 4096 + n0;
  for (int kk = 0; kk < 4; ++kk) {
    bf16x8 pa0 = *(const bf16x8*)&Plds[(ln) * PLDS_STRIDE + kk * 32 + q * 8];
    bf16x8 pa1 = *(const bf16x8*)&Plds[(16 + ln) * PLDS_STRIDE + kk * 32 + q * 8];
    bf16x8 vb[4];
#pragma unroll
    for (int fd = 0; fd < 4; ++fd) {
      const int d = w * 64 + fd * 16 + ln;
      vb[fd] = *(const bf16x8*)(Vtb + (size_t)d * 65536 + kk * 32 + q * 8);
    }
#pragma unroll
    for (int fd = 0; fd < 4; ++fd) {
      acc2[0][fd] = __builtin_amdgcn_mfma_f32_16x16x32_bf16(pa0, vb[fd], acc2[0][fd], 0, 0, 0);
      acc2[1][fd] = __builtin_amdgcn_mfma_f32_16x16x32_bf16(pa1, vb[fd], acc2[1][fd], 0, 0, 0);
    }
  }
#pragma unroll
  for (int fm = 0; fm < 2; ++fm)
#pragma unroll
    for (int fd = 0; fd < 4; ++fd)
#pragma unroll
      for (int r = 0; r < 4; ++r) {
        const int i = fm * 16 + q * 4 + r;
        const int d = w * 64 + fd * 16 + ln;
        atomicAdd(&F1[(size_t)(b * 32 + i) * 256 + d], acc2[fm][fd][r]);
      }
}

// =====================================================================
// Normalize A in place (f32): A = P / rowsum. 4 elems/thread.
// =====================================================================
__global__ __launch_bounds__(256) void norm_a_kernel(float* __restrict__ Aout,
                                                     const float* __restrict__ rowsum) {
  const size_t idx = ((size_t)blockIdx.x * 256 + threadIdx.x) * 4;
  const int row = (int)(idx >> 12);
  const float invs = 1.0f / rowsum[row];
  f32x4 v = *(f32x4*)(Aout + idx);
  v[0] *= invs; v[1] *= invs; v[2] *= invs; v[3] *= invs;
  *(f32x4*)(Aout + idx) = v;
}

// =====================================================================
// Final: F2[m] = (sum_d F1[d]*Wo[m][d]) / rowsum ; out = F2/(||F2||+1e-8)
// one block per output row (b*32+i), 256 threads, 2 m's each. Wo is f32.
// =====================================================================
__global__ __launch_bounds__(256) void final_kernel(const float* __restrict__ F1,
                                                    const float* __restrict__ rowsum,
                                                    const float* __restrict__ Wo,
                                                    float* __restrict__ Fout) {
  __shared__ float fl[256];
  __shared__ float redbuf[4];
  const int row = blockIdx.x;
  const int t = threadIdx.x;
  fl[t] = F1[(size_t)row * 256 + t];
  __syncthreads();
  const float invs = 1.0f / rowsum[row];
  float f2[2];
#pragma unroll
  for (int h = 0; h < 2; ++h) {
    const int m = t + h * 256;
    const float* wr = Wo + (size_t)m * 256;
    float dot = 0.f;
    for (int d = 0; d < 256; d += 4) {
      f32x4 wv = *(const f32x4*)(wr + d);
      dot += wv[0] * fl[d] + wv[1] * fl[d + 1] + wv[2] * fl[d + 2] + wv[3] * fl[d + 3];
    }
    f2[h] = dot * invs;
  }
  float ps = f2[0] * f2[0] + f2[1] * f2[1];
#pragma unroll
  for (int m = 1; m < 64; m <<= 1) ps += __shfl_xor(ps, m, 64);
  if ((t & 63) == 0) redbuf[t >> 6] = ps;
  __syncthreads();
  const float tot = redbuf[0] + redbuf[1] + redbuf[2] + redbuf[3];
  const float sc = 1.0f / (sqrtf(tot) + 1e-8f);
  Fout[(size_t)row * 512 + t] = f2[0] * sc;
  Fout[(size_t)row * 512 + t + 256] = f2[1] * sc;
}

// =====================================================================
extern "C" void kernel_launch(void* const* d_in, const int* in_sizes, int n_in,
                              void* d_out, int out_size, void* d_ws, size_t ws_size,
                              hipStream_t stream) {
  const float* E  = (const float*)d_in[0];  // [16,4096,512]
  const float* T  = (const float*)d_in[1];  // [16,32,512]
  const float* Pb = (const float*)d_in[2];  // [16,4096]
  const float* Wq = (const float*)d_in[3];  // [256,512]
  const float* Wk = (const float*)d_in[4];
  const float* Wv = (const float*)d_in[5];
  const float* Wo = (const float*)d_in[6];  // [512,256]

  float* out  = (float*)d_out;
  float* Fout = out;             // 512*512 f32
  float* Aout = out + 262144;    // 512*4096 f32

  char* ws = (char*)d_ws;
  __bf16* Ebf = (__bf16*)ws;                    // 33554432 elems = 67108864 B
  __bf16* Kp  = (__bf16*)(ws + 67108864);       // [65536][256] bf16 = 33554432 B
  __bf16* Vt  = (__bf16*)(ws + 100663296);      // [256][65536] bf16 = 33554432 B
  __bf16* Tbf = (__bf16*)(ws + 134217728);      // 262144 elems = 524288 B
  __bf16* Wqb = (__bf16*)(ws + 134742016);      // 131072 elems = 262144 B
  __bf16* Wkb = (__bf16*)(ws + 135004160);
  __bf16* Wvb = (__bf16*)(ws + 135266304);
  __bf16* Qw  = (__bf16*)(ws + 135528448);      // [512][256] bf16 = 262144 B
  float*  F1  = (float*)(ws + 135790592);       // [512][256] f32 = 524288 B
  float*  rowsum = (float*)(ws + 136314880);    // [512] f32 (padded to 2048 B)

  hipMemsetAsync(F1, 0, 524288 + 2048, stream);

  // f32 -> bf16 conversions
  cvt_kernel<<<32768, 256, 0, stream>>>(E, Ebf);   // 33554432
  cvt_kernel<<<256, 256, 0, stream>>>(T, Tbf);     // 262144
  cvt_kernel<<<128, 256, 0, stream>>>(Wq, Wqb);    // 131072
  cvt_kernel<<<128, 256, 0, stream>>>(Wk, Wkb);
  cvt_kernel<<<128, 256, 0, stream>>>(Wv, Wvb);

  // Kp[n][d]: A = Wk (m=d, 2 tiles), B = E (n=row, 512 tiles)
  gemm_nt<<<dim3(512, 2), 256, 0, stream>>>(Wkb, Ebf, Kp, 256);
  // Vt[d][row]: A = E (m=row, 512 tiles), B = Wv (n=d, 2 tiles)
  gemm_nt<<<dim3(2, 512), 256, 0, stream>>>(Ebf, Wvb, Vt, 65536);
  // Q[b*32+i][d]: A = Wq (m=d, 2 tiles), B = T (n=row, 4 tiles)
  gemm_nt<<<dim3(4, 2), 256, 0, stream>>>(Wqb, Tbf, Qw, 256);

  attn_kernel<<<dim3(32, 16), 256, 0, stream>>>(Qw, Kp, Vt, Pb, Aout, F1, rowsum);
  norm_a_kernel<<<2048, 256, 0, stream>>>(Aout, rowsum);
  final_kernel<<<512, 256, 0, stream>>>(F1, rowsum, Wo, Fout);
}